// Round 2
// baseline (23930.791 us; speedup 1.0000x reference)
//
#include <hip/hip_runtime.h>

#define NB 128
#define NT 512
#define NE 256
#define NH 512
#define NA 64
#define NG 8      // groups
#define WPG 32    // workgroups per group
#define GB 16     // batches per group

typedef short bf16x8 __attribute__((ext_vector_type(8)));
typedef float f32x4 __attribute__((ext_vector_type(4)));
typedef unsigned short u16x8 __attribute__((ext_vector_type(8)));

__device__ __forceinline__ unsigned short f2bf(float f){
  unsigned u = __builtin_bit_cast(unsigned, f);
  u = u + 0x7fffu + ((u >> 16) & 1u);
  return (unsigned short)(u >> 16);
}
__device__ __forceinline__ float bf2f(unsigned short h){
  unsigned u = ((unsigned)h) << 16;
  return __builtin_bit_cast(float, u);
}
__device__ __forceinline__ bf16x8 packbf2(f32x4 a, f32x4 b){
  bf16x8 r;
  r[0]=(short)f2bf(a[0]); r[1]=(short)f2bf(a[1]); r[2]=(short)f2bf(a[2]); r[3]=(short)f2bf(a[3]);
  r[4]=(short)f2bf(b[0]); r[5]=(short)f2bf(b[1]); r[6]=(short)f2bf(b[2]); r[7]=(short)f2bf(b[3]);
  return r;
}
__device__ __forceinline__ bf16x8 loadB_f32(const float* p){
  f32x4 a = *(const f32x4*)p;
  f32x4 b = *(const f32x4*)(p + 4);
  return packbf2(a, b);
}
#define MFMA(a,b,c) __builtin_amdgcn_mfma_f32_16x16x32_bf16(a,b,c,0,0,0)

__device__ __forceinline__ float fsig(float x){
  return __builtin_amdgcn_rcpf(1.f + __expf(-x));
}
__device__ __forceinline__ float ftanh(float x){
  float e2 = __expf(2.f * x);
  return 1.f - 2.f * __builtin_amdgcn_rcpf(e2 + 1.f);
}

// ---------------------------------------------------------------------------
// Pre-pass: tp[b][t][a] = (embedding[token] . Wt[a,:]) + bt[a], stored bf16.
// MFMA GEMM: M = 65536 positions, N = 64, K = 256.
// ---------------------------------------------------------------------------
__global__ __launch_bounds__(256) void k_tp(
    const int* __restrict__ tok, const float* __restrict__ emb,
    const float* __restrict__ Wt, const float* __restrict__ bt,
    unsigned short* __restrict__ tp)
{
  const int lane = threadIdx.x & 63;
  const int w = threadIdx.x >> 6;
  const int m16 = lane & 15, quad = lane >> 4;

  // B-frags (Wt), shared across all tiles of this wave: B[k=e][n=a] = Wt[a][e]
  bf16x8 wf[8][4];
#pragma unroll
  for (int kc = 0; kc < 8; kc++)
#pragma unroll
    for (int nt = 0; nt < 4; nt++)
      wf[kc][nt] = loadB_f32(Wt + (nt*16 + m16)*NE + kc*32 + quad*8);

  float btv[4];
#pragma unroll
  for (int nt = 0; nt < 4; nt++) btv[nt] = bt[nt*16 + m16];

  const int gw = blockIdx.x * 4 + w;   // 0..1023
#pragma unroll 1
  for (int it = 0; it < 4; it++){
    const int pt = gw * 4 + it;        // position tile 0..4095
    const int pos = pt*16 + m16;
    const long row = (long)tok[pos];
    const float* xrow = emb + row * NE;
    f32x4 acc[4] = {{0,0,0,0},{0,0,0,0},{0,0,0,0},{0,0,0,0}};
#pragma unroll
    for (int kc = 0; kc < 8; kc++){
      bf16x8 af = loadB_f32(xrow + kc*32 + quad*8); // A[m=lane&15][k=quad*8+j]
#pragma unroll
      for (int nt = 0; nt < 4; nt++)
        acc[nt] = MFMA(af, wf[kc][nt], acc[nt]);
    }
#pragma unroll
    for (int nt = 0; nt < 4; nt++)
#pragma unroll
      for (int r = 0; r < 4; r++){
        int posr = pt*16 + quad*4 + r;
        tp[(long)posr * NA + nt*16 + m16] = f2bf(acc[nt][r] + btv[nt]);
      }
  }
}

// ---------------------------------------------------------------------------
// Main persistent kernel (plain launch; per-group spin barriers only).
// ---------------------------------------------------------------------------
struct KArgs {
  const int* len;
  const float* Wq; const float* bq; const float* v; const float* bv;
  const float* Wih0; const float* Whh0; const float* bih0; const float* bhh0;
  const float* Wih1; const float* Whh1; const float* bih1; const float* bhh1;
  const unsigned short* tp;
  float* h0g; float* h1g; float* qg; float* ctxg; float* deng;
  unsigned short* wqblob;
  int* ctrl;
  float* out;
};

__device__ __forceinline__ void gbar(int* cnt, int& ep){
  __syncthreads();
  if (threadIdx.x == 0){
    __threadfence();
    atomicAdd(cnt, 1);
    ep++;
    const int tgt = WPG * ep;
    while (__hip_atomic_load(cnt, __ATOMIC_RELAXED, __HIP_MEMORY_SCOPE_AGENT) < tgt)
      __builtin_amdgcn_s_sleep(2);
    __threadfence();
  }
  __syncthreads();
}

__global__ __launch_bounds__(256, 1) void k_main(KArgs A_)
{
  const int tid = threadIdx.x, lane = tid & 63, w = tid >> 6;
  const int g = blockIdx.x & 7, m = blockIdx.x >> 3;   // group, member
  const int m16 = lane & 15, quad = lane >> 4;

  __shared__ __attribute__((aligned(16))) unsigned short wih1s[3][16][512]; // 48KB frag-ordered
  __shared__ __attribute__((aligned(16))) float dslab[6][256];              // gate D staging

  float* h0g  = A_.h0g  + g * GB * NH;   // [b][dim] fp32
  float* h1g  = A_.h1g  + g * GB * NH;
  float* qg   = A_.qg   + g * GB * NA;   // [b][a] fp32
  float* ctxg = A_.ctxg + g * GB * NA;
  float* deng = A_.deng + g * GB;
  int* bar    = A_.ctrl + g * 64;
  int* qdone  = A_.ctrl + g * 64 + 16;
  const int b0 = g * GB;

  // ----- persistent weight fragments -----
  bf16x8 whh0f[16], whh1f[16], wih0f[2];
  float bhh0v[4], bih0v[4], bhh1v[4], bih1v[4], bqv[4];
  if (w < 3){
    const int r0 = w * NH + m * 16;  // row base within [0,1536)
#pragma unroll
    for (int kc = 0; kc < 16; kc++){
      whh0f[kc] = loadB_f32(A_.Whh0 + (long)(r0 + m16)*NH + kc*32 + quad*8);
      whh1f[kc] = loadB_f32(A_.Whh1 + (long)(r0 + m16)*NH + kc*32 + quad*8);
      bf16x8 t  = loadB_f32(A_.Wih1 + (long)(r0 + m16)*NH + kc*32 + quad*8);
      *(bf16x8*)&wih1s[w][kc][lane*8] = t;
    }
#pragma unroll
    for (int kc = 0; kc < 2; kc++)
      wih0f[kc] = loadB_f32(A_.Wih0 + (r0 + m16)*NA + kc*32 + quad*8);
#pragma unroll
    for (int r = 0; r < 4; r++){
      int d = r0 + quad*4 + r;
      bhh0v[r] = A_.bhh0[d]; bih0v[r] = A_.bih0[d];
      bhh1v[r] = A_.bhh1[d]; bih1v[r] = A_.bih1[d];
    }
  }
  if (w == 3 && m < 4){
    // pack Wq frag blob (same data from every group: benign identical writes)
#pragma unroll
    for (int kc = 0; kc < 16; kc++){
      bf16x8 t = loadB_f32(A_.Wq + (long)(m*16 + m16)*NH + kc*32 + quad*8);
      *(bf16x8*)&A_.wqblob[((m*16 + kc)*64 + lane)*8] = t;
    }
#pragma unroll
    for (int r = 0; r < 4; r++) bqv[r] = A_.bq[m*16 + quad*4 + r];
  }

  // attention constants: lane = (a4=quad, t16=m16), wave handles batch ab
  float vv[16];
#pragma unroll
  for (int jj = 0; jj < 16; jj++) vv[jj] = A_.v[quad*16 + jj];
  const float bvv = A_.bv[0];
  const int gwav = m*4 + w;
  const int ab = gwav & 15;   // batch within group
  const int wr = gwav >> 4;   // 0..7 chunk phase

  // ----- init global state -----
  f32x4 h0p = {0,0,0,0}, h1p = {0,0,0,0};
  if (w == 3){
    f32x4 z = {0,0,0,0};
    *(f32x4*)&h0g[m16*NH + m*16 + quad*4] = z;
    *(f32x4*)&h1g[m16*NH + m*16 + quad*4] = z;
  }
  if (w == 1){
    if (lane < 32) ctxg[m*32 + lane] = 0.f;
    if (lane == 32 && m < GB) deng[m] = 0.f;
  }

  // lengths -> per-batch output step + group max
  int myidx = 0, imax = 0;
#pragma unroll 1
  for (int b = 0; b < GB; b++){
    int L = A_.len[b0 + b];
    int ix = L - 2; ix = ix < 0 ? 0 : (ix > NT-1 ? NT-1 : ix);
    if (b == m16) myidx = ix;
    imax = imax > ix ? imax : ix;
  }

  int ep = 0;
  gbar(bar, ep);   // init barrier: weights packed, state zeroed

#pragma unroll 1
  for (int i = 0; i <= imax; i++){
    // =================== P1: gh0, gh1 (+ q by 4 producer WGs) ===================
    f32x4 gh1 = {0,0,0,0};
    if (w < 3){
      f32x4 gh0 = {0,0,0,0};
      const float* hb0 = h0g + m16*NH;
      const float* hb1 = h1g + m16*NH;
#pragma unroll
      for (int kc = 0; kc < 16; kc++){
        bf16x8 bf0 = loadB_f32(hb0 + kc*32 + quad*8);
        gh0 = MFMA(whh0f[kc], bf0, gh0);
        bf16x8 bf1 = loadB_f32(hb1 + kc*32 + quad*8);
        gh1 = MFMA(whh1f[kc], bf1, gh1);
      }
#pragma unroll
      for (int r = 0; r < 4; r++){ gh0[r] += bhh0v[r]; gh1[r] += bhh1v[r]; }
      *(f32x4*)&dslab[w][lane*4] = gh0;
    } else if (m < 4){
      f32x4 qa = {0,0,0,0};
      const float* hb1 = h1g + m16*NH;
#pragma unroll
      for (int kc = 0; kc < 16; kc++){
        bf16x8 af = *(const bf16x8*)&A_.wqblob[((m*16 + kc)*64 + lane)*8];
        bf16x8 bf1 = loadB_f32(hb1 + kc*32 + quad*8);
        qa = MFMA(af, bf1, qa);
      }
#pragma unroll
      for (int r = 0; r < 4; r++) qa[r] += bqv[r];
      *(f32x4*)&qg[m16*NA + m*16 + quad*4] = qa;   // q[b][a]
      __threadfence();
      if (lane == 0) atomicAdd(qdone, 1);
    }

    // q-ready spin (producer->consumer, cheaper than a full barrier)
    __syncthreads();
    if (tid == 0){
      const int tgt = 4*(i+1);
      while (__hip_atomic_load(qdone, __ATOMIC_RELAXED, __HIP_MEMORY_SCOPE_AGENT) < tgt)
        __builtin_amdgcn_s_sleep(1);
      __threadfence();
    }
    __syncthreads();

    // =================== P2: attention for batch ab ===================
    float qv[16];
#pragma unroll
    for (int jq = 0; jq < 4; jq++){
      f32x4 t = *(const f32x4*)&qg[ab*NA + quad*16 + jq*4];
      qv[jq*4+0]=t[0]; qv[jq*4+1]=t[1]; qv[jq*4+2]=t[2]; qv[jq*4+3]=t[3];
    }
    float ctxp[16];
#pragma unroll
    for (int jj = 0; jj < 16; jj++) ctxp[jj] = 0.f;
    float denp = 0.f;
    const unsigned short* tpb = A_.tp + (long)(b0 + ab) * NT * NA;
#pragma unroll 1
    for (int c = wr; c*16 <= i; c += 8){
      const int t = c*16 + m16;
      const unsigned short* tpp = tpb + (long)t*NA + quad*16;
      u16x8 ta = *(const u16x8*)tpp;
      u16x8 tb = *(const u16x8*)(tpp + 8);
      float tpf[16];
#pragma unroll
      for (int jj = 0; jj < 8; jj++){ tpf[jj] = bf2f(ta[jj]); tpf[8+jj] = bf2f(tb[jj]); }
      float sp = 0.f;
#pragma unroll
      for (int jj = 0; jj < 16; jj++){
        float x = tpf[jj] + qv[jj];
        sp = fmaf(ftanh(x), vv[jj], sp);
      }
      sp += __shfl_xor(sp, 16);
      sp += __shfl_xor(sp, 32);
      float e = __expf(sp + bvv);
      e = (t <= i) ? e : 0.f;
      denp += e;
#pragma unroll
      for (int jj = 0; jj < 16; jj++) ctxp[jj] = fmaf(e, tpf[jj], ctxp[jj]);
    }
    // den: sum 64 lanes (each t duplicated over 4 a4-lanes) -> /4
#pragma unroll
    for (int off = 1; off < 64; off <<= 1) denp += __shfl_xor(denp, off);
    denp *= 0.25f;
    // ctx: transpose-reduce over the 16 t16-lanes; lane l ends with a = l
#pragma unroll
    for (int st = 0; st < 4; st++){
      const int bit = 1 << st;
      const bool up = (lane >> st) & 1;
      const int n2 = (16 >> st) >> 1;
#pragma unroll
      for (int j2 = 0; j2 < 8; j2++){
        if (j2 < n2){
          float keep = up ? ctxp[2*j2+1] : ctxp[2*j2];
          float send = up ? ctxp[2*j2]   : ctxp[2*j2+1];
          float got = __shfl_xor(send, bit);
          ctxp[j2] = keep + got;
        }
      }
    }
    atomicAdd(&ctxg[ab*NA + lane], ctxp[0]);
    if (lane == 0) atomicAdd(&deng[ab], denp);

    gbar(bar, ep);   // S2: ctx/den complete

    // =================== P3: gi0 + layer-0 combine ===================
    if (w < 3){
      f32x4 gi0 = {0,0,0,0};
      const float dn = deng[m16];
      const float rdn = 1.0f / dn;
#pragma unroll
      for (int kc = 0; kc < 2; kc++){
        const float* cp = &ctxg[m16*NA + kc*32 + quad*8];
        f32x4 c0 = *(const f32x4*)cp;
        f32x4 c1 = *(const f32x4*)(cp + 4);
#pragma unroll
        for (int r = 0; r < 4; r++){ c0[r] *= rdn; c1[r] *= rdn; }
        gi0 = MFMA(wih0f[kc], packbf2(c0, c1), gi0);
      }
#pragma unroll
      for (int r = 0; r < 4; r++) gi0[r] += bih0v[r];
      *(f32x4*)&dslab[3+w][lane*4] = gi0;
    }
    __syncthreads();
    if (w == 3){
      f32x4 ghr = *(f32x4*)&dslab[0][lane*4];
      f32x4 ghz = *(f32x4*)&dslab[1][lane*4];
      f32x4 ghn = *(f32x4*)&dslab[2][lane*4];
      f32x4 gir = *(f32x4*)&dslab[3][lane*4];
      f32x4 giz = *(f32x4*)&dslab[4][lane*4];
      f32x4 gin = *(f32x4*)&dslab[5][lane*4];
      f32x4 hn;
#pragma unroll
      for (int r = 0; r < 4; r++){
        float rr = fsig(gir[r] + ghr[r]);
        float zz = fsig(giz[r] + ghz[r]);
        float nn = ftanh(gin[r] + rr*ghn[r]);
        hn[r] = (1.f - zz)*nn + zz*h0p[r];
      }
      h0p = hn;
      *(f32x4*)&h0g[m16*NH + m*16 + quad*4] = hn;
    }
    gbar(bar, ep);   // S3: h0 published

    // =================== P4: gi1 + layer-1 combine ===================
    if (w < 3){
      f32x4 gi1 = {0,0,0,0};
      const float* hb0 = h0g + m16*NH;
#pragma unroll
      for (int kc = 0; kc < 16; kc++){
        bf16x8 af = *(const bf16x8*)&wih1s[w][kc][lane*8];
        bf16x8 bfr = loadB_f32(hb0 + kc*32 + quad*8);
        gi1 = MFMA(af, bfr, gi1);
      }
#pragma unroll
      for (int r = 0; r < 4; r++) gi1[r] += bih1v[r];
      *(f32x4*)&dslab[w][lane*4] = gh1;
      *(f32x4*)&dslab[3+w][lane*4] = gi1;
    }
    if (w == 1){
      // clear ctx/den for next step (readers finished before S3)
      if (lane < 32) ctxg[m*32 + lane] = 0.f;
      if (lane == 32 && m < GB) deng[m] = 0.f;
    }
    __syncthreads();
    if (w == 3){
      f32x4 ghr = *(f32x4*)&dslab[0][lane*4];
      f32x4 ghz = *(f32x4*)&dslab[1][lane*4];
      f32x4 ghn = *(f32x4*)&dslab[2][lane*4];
      f32x4 gir = *(f32x4*)&dslab[3][lane*4];
      f32x4 giz = *(f32x4*)&dslab[4][lane*4];
      f32x4 gin = *(f32x4*)&dslab[5][lane*4];
      f32x4 hn;
#pragma unroll
      for (int r = 0; r < 4; r++){
        float rr = fsig(gir[r] + ghr[r]);
        float zz = fsig(giz[r] + ghz[r]);
        float nn = ftanh(gin[r] + rr*ghn[r]);
        hn[r] = (1.f - zz)*nn + zz*h1p[r];
      }
      h1p = hn;
      *(f32x4*)&h1g[m16*NH + m*16 + quad*4] = hn;
      if (i == myidx)
        *(f32x4*)&A_.out[(long)(b0 + m16)*NH + m*16 + quad*4] = hn;
    }
    gbar(bar, ep);   // S4: h1 published
  }
}

// ---------------------------------------------------------------------------
extern "C" void kernel_launch(void* const* d_in, const int* in_sizes, int n_in,
                              void* d_out, int out_size, void* d_ws, size_t ws_size,
                              hipStream_t stream)
{
  (void)in_sizes; (void)n_in; (void)out_size; (void)ws_size;
  char* ws = (char*)d_ws;
  unsigned short* tp = (unsigned short*)ws;                 // 8 MB
  float* h0g  = (float*)(ws + 8388608);                     // 256 KB
  float* h1g  = h0g + NG*GB*NH;                             // 256 KB
  float* qg   = h1g + NG*GB*NH;                             // 32 KB
  float* ctxg = qg  + NG*GB*NA;                             // 32 KB
  float* deng = ctxg+ NG*GB*NA;                             // padded 4 KB
  unsigned short* wqblob = (unsigned short*)(deng + 1024);  // 64 KB
  int* ctrl = (int*)((char*)wqblob + 65536);                // 2 KB

  hipMemsetAsync(ctrl, 0, 2048, stream);

  k_tp<<<dim3(256), dim3(256), 0, stream>>>(
      (const int*)d_in[0], (const float*)d_in[2], (const float*)d_in[3],
      (const float*)d_in[4], tp);

  KArgs ka;
  ka.len  = (const int*)d_in[1];
  ka.Wq   = (const float*)d_in[5];  ka.bq   = (const float*)d_in[6];
  ka.v    = (const float*)d_in[7];  ka.bv   = (const float*)d_in[8];
  ka.Wih0 = (const float*)d_in[9];  ka.Whh0 = (const float*)d_in[10];
  ka.bih0 = (const float*)d_in[11]; ka.bhh0 = (const float*)d_in[12];
  ka.Wih1 = (const float*)d_in[13]; ka.Whh1 = (const float*)d_in[14];
  ka.bih1 = (const float*)d_in[15]; ka.bhh1 = (const float*)d_in[16];
  ka.tp = tp; ka.h0g = h0g; ka.h1g = h1g; ka.qg = qg; ka.ctxg = ctxg; ka.deng = deng;
  ka.wqblob = wqblob; ka.ctrl = ctrl; ka.out = (float*)d_out;

  k_main<<<dim3(256), dim3(256), 0, stream>>>(ka);
}

// Round 6
// 14072.092 us; speedup vs baseline: 1.7006x; 1.7006x over previous
//
#include <hip/hip_runtime.h>

#define NB 128
#define NT 512
#define NE 256
#define NH 512
#define NA 64
#define NG 8      // groups (one per XCD via blockIdx%8)
#define WPG 32    // workgroups per group
#define GB 16     // batches per group

typedef short bf16x8 __attribute__((ext_vector_type(8)));
typedef float f32x4 __attribute__((ext_vector_type(4)));
typedef unsigned short u16x8 __attribute__((ext_vector_type(8)));

__device__ __forceinline__ unsigned short f2bf(float f){
  unsigned u = __builtin_bit_cast(unsigned, f);
  u = u + 0x7fffu + ((u >> 16) & 1u);
  return (unsigned short)(u >> 16);
}
__device__ __forceinline__ float bf2f(unsigned short h){
  unsigned u = ((unsigned)h) << 16;
  return __builtin_bit_cast(float, u);
}
__device__ __forceinline__ bf16x8 packbf2(f32x4 a, f32x4 b){
  bf16x8 r;
  r[0]=(short)f2bf(a[0]); r[1]=(short)f2bf(a[1]); r[2]=(short)f2bf(a[2]); r[3]=(short)f2bf(a[3]);
  r[4]=(short)f2bf(b[0]); r[5]=(short)f2bf(b[1]); r[6]=(short)f2bf(b[2]); r[7]=(short)f2bf(b[3]);
  return r;
}
__device__ __forceinline__ bf16x8 loadB_f32(const float* p){
  f32x4 a = *(const f32x4*)p;
  f32x4 b = *(const f32x4*)(p + 4);
  return packbf2(a, b);
}
#define MFMA(a,b,c) __builtin_amdgcn_mfma_f32_16x16x32_bf16(a,b,c,0,0,0)

__device__ __forceinline__ float fsig(float x){
  return __builtin_amdgcn_rcpf(1.f + __expf(-x));
}
__device__ __forceinline__ float ftanh(float x){
  float e2 = __expf(2.f * x);
  return 1.f - 2.f * __builtin_amdgcn_rcpf(e2 + 1.f);
}

// ---- coherent (LLC-visible) helpers: relaxed agent-scope atomics (sc1) ----
__device__ __forceinline__ bf16x8 aload_bf8(const unsigned short* p){
  union { unsigned long long u[2]; bf16x8 v; } t;
  t.u[0] = __hip_atomic_load((const unsigned long long*)p,     __ATOMIC_RELAXED, __HIP_MEMORY_SCOPE_AGENT);
  t.u[1] = __hip_atomic_load((const unsigned long long*)(p+4), __ATOMIC_RELAXED, __HIP_MEMORY_SCOPE_AGENT);
  return t.v;
}
__device__ __forceinline__ void astore_bf4(unsigned short* p, f32x4 x){
  union { unsigned short s[4]; unsigned long long u; } t;
  t.s[0]=f2bf(x[0]); t.s[1]=f2bf(x[1]); t.s[2]=f2bf(x[2]); t.s[3]=f2bf(x[3]);
  __hip_atomic_store((unsigned long long*)p, t.u, __ATOMIC_RELAXED, __HIP_MEMORY_SCOPE_AGENT);
}
struct fpair { float x, y; };
__device__ __forceinline__ fpair aload_f2(const float* p){
  unsigned long long u = __hip_atomic_load((const unsigned long long*)p, __ATOMIC_RELAXED, __HIP_MEMORY_SCOPE_AGENT);
  fpair r;
  r.x = __builtin_bit_cast(float, (unsigned)u);
  r.y = __builtin_bit_cast(float, (unsigned)(u >> 32));
  return r;
}
__device__ __forceinline__ float aload_f(const float* p){
  return __hip_atomic_load(p, __ATOMIC_RELAXED, __HIP_MEMORY_SCOPE_AGENT);
}
__device__ __forceinline__ void azero8(unsigned long long* p){
  __hip_atomic_store(p, 0ull, __ATOMIC_RELAXED, __HIP_MEMORY_SCOPE_AGENT);
}

// ---------------------------------------------------------------------------
// Pre-pass: tp[pos][a] = (embedding[token] . Wt[a,:]) + bt[a], stored bf16.
// ---------------------------------------------------------------------------
__global__ __launch_bounds__(256) void k_tp(
    const int* __restrict__ tok, const float* __restrict__ emb,
    const float* __restrict__ Wt, const float* __restrict__ bt,
    unsigned short* __restrict__ tp)
{
  const int lane = threadIdx.x & 63;
  const int w = threadIdx.x >> 6;
  const int m16 = lane & 15, quad = lane >> 4;

  bf16x8 wfq[8][4];
#pragma unroll
  for (int kc = 0; kc < 8; kc++)
#pragma unroll
    for (int nt = 0; nt < 4; nt++)
      wfq[kc][nt] = loadB_f32(Wt + (nt*16 + m16)*NE + kc*32 + quad*8);

  float btv[4];
#pragma unroll
  for (int nt = 0; nt < 4; nt++) btv[nt] = bt[nt*16 + m16];

  const int gw = blockIdx.x * 4 + w;
#pragma unroll 1
  for (int it = 0; it < 4; it++){
    const int pt = gw * 4 + it;
    const int pos = pt*16 + m16;
    const long row = (long)tok[pos];
    const float* xrow = emb + row * NE;
    f32x4 acc[4] = {{0,0,0,0},{0,0,0,0},{0,0,0,0},{0,0,0,0}};
#pragma unroll
    for (int kc = 0; kc < 8; kc++){
      bf16x8 af = loadB_f32(xrow + kc*32 + quad*8);
#pragma unroll
      for (int nt = 0; nt < 4; nt++)
        acc[nt] = MFMA(af, wfq[kc][nt], acc[nt]);
    }
#pragma unroll
    for (int nt = 0; nt < 4; nt++)
#pragma unroll
      for (int r = 0; r < 4; r++){
        int posr = pt*16 + quad*4 + r;
        tp[(long)posr * NA + nt*16 + m16] = f2bf(acc[nt][r] + btv[nt]);
      }
  }
}

// ---------------------------------------------------------------------------
struct KArgs {
  const int* len;
  const float* Wq; const float* bq; const float* v; const float* bv;
  const float* Wih0; const float* Whh0; const float* bih0; const float* bhh0;
  const float* Wih1; const float* Whh1; const float* bih1; const float* bhh1;
  const unsigned short* tp;
  unsigned short* h0b; unsigned short* h1b;
  float* ctxg; float* deng;
  int* ctrl;
  float* out;
};

// Group barrier with message-passing ordering: release fence before the
// arrive-add, acquire fence after the poll. Data path is sc1 write-through
// so the release's L2 writeback has almost nothing to drain.
__device__ __forceinline__ void gbar(int* cnt, int& ep){
  __syncthreads();
  ep++;
  if (threadIdx.x == 0){
    __builtin_amdgcn_fence(__ATOMIC_RELEASE, "agent");
    __hip_atomic_fetch_add(cnt, 1, __ATOMIC_RELAXED, __HIP_MEMORY_SCOPE_AGENT);
    const int tgt = WPG * ep;
    while (__hip_atomic_load(cnt, __ATOMIC_RELAXED, __HIP_MEMORY_SCOPE_AGENT) < tgt)
      __builtin_amdgcn_s_sleep(1);
    __builtin_amdgcn_fence(__ATOMIC_ACQUIRE, "agent");
  }
  __syncthreads();
}

__global__ __launch_bounds__(256, 1) void k_main(KArgs A_)
{
  const int tid = threadIdx.x, lane = tid & 63, w = tid >> 6;
  const int g = blockIdx.x & 7, m = blockIdx.x >> 3;   // group, member
  const int m16 = lane & 15, quad = lane >> 4;

  __shared__ __attribute__((aligned(16))) float dslab[6][256]; // gate D staging
  __shared__ __attribute__((aligned(16))) float qs[16][68];    // q[b][a], padded

  unsigned short* h0b = A_.h0b + g * GB * NH;   // bf16 [b][dim]
  unsigned short* h1b = A_.h1b + g * GB * NH;
  float* ctxg = A_.ctxg + g * GB * NA;
  float* deng = A_.deng + g * GB;
  int* bar    = A_.ctrl + g * 64;
  const int b0 = g * GB;

  // ----- persistent weight fragments (registers; 1 block/CU by design) -----
  // w<3 : wf[0..15]=Whh0, wf[16..31]=Whh1, wf[32..47]=Wih1 (rows w*512+m*16)
  // w==3: wf[nt*16+kc]=Wq (all 64 rows)
  bf16x8 wf[64], wih0f[2];
  float bhh0v[4], bih0v[4], bhh1v[4], bih1v[4], bqv2[4][4];
  if (w < 3){
    const int r0 = w * NH + m * 16;
#pragma unroll
    for (int kc = 0; kc < 16; kc++){
      wf[kc]    = loadB_f32(A_.Whh0 + (long)(r0 + m16)*NH + kc*32 + quad*8);
      wf[16+kc] = loadB_f32(A_.Whh1 + (long)(r0 + m16)*NH + kc*32 + quad*8);
      wf[32+kc] = loadB_f32(A_.Wih1 + (long)(r0 + m16)*NH + kc*32 + quad*8);
    }
#pragma unroll
    for (int kc = 0; kc < 2; kc++)
      wih0f[kc] = loadB_f32(A_.Wih0 + (r0 + m16)*NA + kc*32 + quad*8);
#pragma unroll
    for (int r = 0; r < 4; r++){
      int d = r0 + quad*4 + r;
      bhh0v[r] = A_.bhh0[d]; bih0v[r] = A_.bih0[d];
      bhh1v[r] = A_.bhh1[d]; bih1v[r] = A_.bih1[d];
    }
  } else {
#pragma unroll
    for (int nt = 0; nt < 4; nt++){
#pragma unroll
      for (int kc = 0; kc < 16; kc++)
        wf[nt*16+kc] = loadB_f32(A_.Wq + (long)(nt*16 + m16)*NH + kc*32 + quad*8);
#pragma unroll
      for (int r = 0; r < 4; r++) bqv2[nt][r] = A_.bq[nt*16 + quad*4 + r];
    }
  }

  // attention constants: lane = (a4=quad, t16=m16); wave handles batch ab
  float vv[16];
#pragma unroll
  for (int jj = 0; jj < 16; jj++) vv[jj] = A_.v[quad*16 + jj];
  const float bvv = A_.bv[0];
  const int gwav = m*4 + w;
  const int ab = gwav & 15;   // batch within group
  const int wr = gwav >> 4;   // chunk phase 0..7

  // ----- init shared state (coherent stores) -----
  f32x4 h0p = {0,0,0,0}, h1p = {0,0,0,0};
  if (w == 3){
    f32x4 z = {0,0,0,0};
    astore_bf4(&h0b[m16*NH + m*16 + quad*4], z);
    astore_bf4(&h1b[m16*NH + m*16 + quad*4], z);
  }
  if (w == 1){
    // full clear: 32 blocks x 16 qwords = 512 qwords = GB*NA floats
    if (lane < 16) azero8((unsigned long long*)ctxg + m*16 + lane);
    if (lane == 16 && m < 8) azero8((unsigned long long*)deng + m);
  }

  // lengths -> per-batch output step + group max
  int myidx = 0, imax = 0;
#pragma unroll 1
  for (int b = 0; b < GB; b++){
    int L = A_.len[b0 + b];
    int ix = L - 2; ix = ix < 0 ? 0 : (ix > NT-1 ? NT-1 : ix);
    if (b == m16) myidx = ix;
    imax = imax > ix ? imax : ix;
  }

  int ep = 0;
  gbar(bar, ep);   // init barrier

#pragma unroll 1
  for (int i = 0; i <= imax; i++){
    const unsigned short* hb0 = h0b + m16*NH;
    const unsigned short* hb1 = h1b + m16*NH;
    // ============ Phase A: gh0, gh1 (w<3) / q (w==3) ============
    f32x4 gh1 = {0,0,0,0};
    if (w < 3){
      f32x4 gh0 = {0,0,0,0};
#pragma unroll
      for (int kc = 0; kc < 16; kc++){
        bf16x8 b0f = aload_bf8(hb0 + kc*32 + quad*8);
        gh0 = MFMA(wf[kc], b0f, gh0);
        bf16x8 b1f = aload_bf8(hb1 + kc*32 + quad*8);
        gh1 = MFMA(wf[16+kc], b1f, gh1);
      }
#pragma unroll
      for (int r = 0; r < 4; r++){ gh0[r] += bhh0v[r]; gh1[r] += bhh1v[r]; }
      *(f32x4*)&dslab[w][lane*4] = gh0;
    } else {
      bf16x8 b1f[16];
#pragma unroll
      for (int kc = 0; kc < 16; kc++) b1f[kc] = aload_bf8(hb1 + kc*32 + quad*8);
#pragma unroll
      for (int nt = 0; nt < 4; nt++){
        f32x4 qa = {0,0,0,0};
#pragma unroll
        for (int kc = 0; kc < 16; kc++)
          qa = MFMA(wf[nt*16+kc], b1f[kc], qa);
#pragma unroll
        for (int r = 0; r < 4; r++)
          qs[m16][nt*16 + quad*4 + r] = qa[r] + bqv2[nt][r];
      }
    }
    __syncthreads();   // q ready in LDS

    // ============ Phase B: attention for batch ab ============
    float qv[16];
#pragma unroll
    for (int jq = 0; jq < 4; jq++){
      f32x4 t = *(const f32x4*)&qs[ab][quad*16 + jq*4];
      qv[jq*4+0]=t[0]; qv[jq*4+1]=t[1]; qv[jq*4+2]=t[2]; qv[jq*4+3]=t[3];
    }
    float ctxp[16];
#pragma unroll
    for (int jj = 0; jj < 16; jj++) ctxp[jj] = 0.f;
    float denp = 0.f;
    const unsigned short* tpb = A_.tp + (long)(b0 + ab) * NT * NA;
#pragma unroll 1
    for (int c = wr; c*16 <= i; c += 8){
      const int t = c*16 + m16;
      const unsigned short* tpp = tpb + (long)t*NA + quad*16;
      u16x8 ta = *(const u16x8*)tpp;
      u16x8 tb = *(const u16x8*)(tpp + 8);
      float tpf[16];
#pragma unroll
      for (int jj = 0; jj < 8; jj++){ tpf[jj] = bf2f(ta[jj]); tpf[8+jj] = bf2f(tb[jj]); }
      float sp = 0.f;
#pragma unroll
      for (int jj = 0; jj < 16; jj++){
        float x = tpf[jj] + qv[jj];
        sp = fmaf(ftanh(x), vv[jj], sp);
      }
      sp += __shfl_xor(sp, 16);
      sp += __shfl_xor(sp, 32);
      float e = __expf(sp + bvv);
      e = (t <= i) ? e : 0.f;
      denp += e;
#pragma unroll
      for (int jj = 0; jj < 16; jj++) ctxp[jj] = fmaf(e, tpf[jj], ctxp[jj]);
    }
#pragma unroll
    for (int off = 1; off < 64; off <<= 1) denp += __shfl_xor(denp, off);
    denp *= 0.25f;
#pragma unroll
    for (int st = 0; st < 4; st++){
      const int bit = 1 << st;
      const bool up = (lane >> st) & 1;
      const int n2 = (16 >> st) >> 1;
#pragma unroll
      for (int j2 = 0; j2 < 8; j2++){
        if (j2 < n2){
          float keep = up ? ctxp[2*j2+1] : ctxp[2*j2];
          float send = up ? ctxp[2*j2]   : ctxp[2*j2+1];
          float got = __shfl_xor(send, bit);
          ctxp[j2] = keep + got;
        }
      }
    }
    atomicAdd(&ctxg[ab*NA + lane], ctxp[0]);
    if (lane == 0) atomicAdd(&deng[ab], denp);

    gbar(bar, ep);   // J2: ctx/den complete

    // ============ Phase C: gi0 + layer-0 combine ============
    if (w < 3){
      f32x4 gi0 = {0,0,0,0};
      const float rdn = 1.0f / aload_f(&deng[m16]);
#pragma unroll
      for (int kc = 0; kc < 2; kc++){
        const float* cp = &ctxg[m16*NA + kc*32 + quad*8];
        f32x4 c0, c1;
        fpair p0 = aload_f2(cp+0); c0[0]=p0.x; c0[1]=p0.y;
        fpair p1 = aload_f2(cp+2); c0[2]=p1.x; c0[3]=p1.y;
        fpair p2 = aload_f2(cp+4); c1[0]=p2.x; c1[1]=p2.y;
        fpair p3 = aload_f2(cp+6); c1[2]=p3.x; c1[3]=p3.y;
#pragma unroll
        for (int r = 0; r < 4; r++){ c0[r] *= rdn; c1[r] *= rdn; }
        gi0 = MFMA(wih0f[kc], packbf2(c0, c1), gi0);
      }
#pragma unroll
      for (int r = 0; r < 4; r++) gi0[r] += bih0v[r];
      *(f32x4*)&dslab[3+w][lane*4] = gi0;
    }
    __syncthreads();
    if (w == 3){
      f32x4 ghr = *(f32x4*)&dslab[0][lane*4];
      f32x4 ghz = *(f32x4*)&dslab[1][lane*4];
      f32x4 ghn = *(f32x4*)&dslab[2][lane*4];
      f32x4 gir = *(f32x4*)&dslab[3][lane*4];
      f32x4 giz = *(f32x4*)&dslab[4][lane*4];
      f32x4 gin = *(f32x4*)&dslab[5][lane*4];
      f32x4 hn;
#pragma unroll
      for (int r = 0; r < 4; r++){
        float rr = fsig(gir[r] + ghr[r]);
        float zz = fsig(giz[r] + ghz[r]);
        float nn = ftanh(gin[r] + rr*ghn[r]);
        hn[r] = (1.f - zz)*nn + zz*h0p[r];
      }
      h0p = hn;
      astore_bf4(&h0b[m16*NH + m*16 + quad*4], hn);
    }
    gbar(bar, ep);   // J3: h0 published

    // ============ Phase D: gi1 + layer-1 combine ============
    if (w < 3){
      f32x4 gi1 = {0,0,0,0};
#pragma unroll
      for (int kc = 0; kc < 16; kc++){
        bf16x8 bfr = aload_bf8(hb0 + kc*32 + quad*8);
        gi1 = MFMA(wf[32+kc], bfr, gi1);
      }
#pragma unroll
      for (int r = 0; r < 4; r++) gi1[r] += bih1v[r];
      *(f32x4*)&dslab[w][lane*4] = gh1;
      *(f32x4*)&dslab[3+w][lane*4] = gi1;
    }
    if (w == 1){
      // full clear of ctx/den for next step (readers done before J3)
      if (lane < 16) azero8((unsigned long long*)ctxg + m*16 + lane);
      if (lane == 16 && m < 8) azero8((unsigned long long*)deng + m);
    }
    __syncthreads();
    if (w == 3){
      f32x4 ghr = *(f32x4*)&dslab[0][lane*4];
      f32x4 ghz = *(f32x4*)&dslab[1][lane*4];
      f32x4 ghn = *(f32x4*)&dslab[2][lane*4];
      f32x4 gir = *(f32x4*)&dslab[3][lane*4];
      f32x4 giz = *(f32x4*)&dslab[4][lane*4];
      f32x4 gin = *(f32x4*)&dslab[5][lane*4];
      f32x4 hn;
#pragma unroll
      for (int r = 0; r < 4; r++){
        float rr = fsig(gir[r] + ghr[r]);
        float zz = fsig(giz[r] + ghz[r]);
        float nn = ftanh(gin[r] + rr*ghn[r]);
        hn[r] = (1.f - zz)*nn + zz*h1p[r];
      }
      h1p = hn;
      astore_bf4(&h1b[m16*NH + m*16 + quad*4], hn);
      if (i == myidx)
        *(f32x4*)&A_.out[(long)(b0 + m16)*NH + m*16 + quad*4] = hn;
    }
    gbar(bar, ep);   // J4: h1 published
  }
}

// ---------------------------------------------------------------------------
extern "C" void kernel_launch(void* const* d_in, const int* in_sizes, int n_in,
                              void* d_out, int out_size, void* d_ws, size_t ws_size,
                              hipStream_t stream)
{
  (void)in_sizes; (void)n_in; (void)out_size; (void)ws_size;
  char* ws = (char*)d_ws;
  unsigned short* tp  = (unsigned short*)ws;                   // 8 MB
  unsigned short* h0b = (unsigned short*)(ws + 8388608);       // 128 KB
  unsigned short* h1b = h0b + NB*NH;                           // 128 KB
  float* ctxg = (float*)(h1b + NB*NH);                         // 32 KB
  float* deng = ctxg + NB*NA;                                  // 512 B -> pad 4 KB
  int* ctrl   = (int*)((char*)deng + 4096);                    // 2 KB

  (void)hipMemsetAsync(ctrl, 0, 2048, stream);

  k_tp<<<dim3(256), dim3(256), 0, stream>>>(
      (const int*)d_in[0], (const float*)d_in[2], (const float*)d_in[3],
      (const float*)d_in[4], tp);

  KArgs ka;
  ka.len  = (const int*)d_in[1];
  ka.Wq   = (const float*)d_in[5];  ka.bq   = (const float*)d_in[6];
  ka.v    = (const float*)d_in[7];  ka.bv   = (const float*)d_in[8];
  ka.Wih0 = (const float*)d_in[9];  ka.Whh0 = (const float*)d_in[10];
  ka.bih0 = (const float*)d_in[11]; ka.bhh0 = (const float*)d_in[12];
  ka.Wih1 = (const float*)d_in[13]; ka.Whh1 = (const float*)d_in[14];
  ka.bih1 = (const float*)d_in[15]; ka.bhh1 = (const float*)d_in[16];
  ka.tp = tp; ka.h0b = h0b; ka.h1b = h1b; ka.ctxg = ctxg; ka.deng = deng;
  ka.ctrl = ctrl; ka.out = (float*)d_out;

  k_main<<<dim3(256), dim3(256), 0, stream>>>(ka);
}

// Round 8
// 10959.689 us; speedup vs baseline: 2.1835x; 1.2840x over previous
//
#include <hip/hip_runtime.h>

#define NB 128
#define NT 512
#define NE 256
#define NH 512
#define NA 64
#define NG 8      // groups (one per XCD via blockIdx%8)
#define WPG 32    // workgroups per group
#define GB 16     // batches per group

typedef short bf16x8 __attribute__((ext_vector_type(8)));
typedef float f32x4 __attribute__((ext_vector_type(4)));
typedef unsigned short u16x8 __attribute__((ext_vector_type(8)));
typedef unsigned long long u64;

__device__ __forceinline__ unsigned short f2bf(float f){
  unsigned u = __builtin_bit_cast(unsigned, f);
  u = u + 0x7fffu + ((u >> 16) & 1u);
  return (unsigned short)(u >> 16);
}
__device__ __forceinline__ float bf2f(unsigned short h){
  unsigned u = ((unsigned)h) << 16;
  return __builtin_bit_cast(float, u);
}
__device__ __forceinline__ bf16x8 packbf2(f32x4 a, f32x4 b){
  bf16x8 r;
  r[0]=(short)f2bf(a[0]); r[1]=(short)f2bf(a[1]); r[2]=(short)f2bf(a[2]); r[3]=(short)f2bf(a[3]);
  r[4]=(short)f2bf(b[0]); r[5]=(short)f2bf(b[1]); r[6]=(short)f2bf(b[2]); r[7]=(short)f2bf(b[3]);
  return r;
}
__device__ __forceinline__ bf16x8 loadB_f32(const float* p){
  f32x4 a = *(const f32x4*)p;
  f32x4 b = *(const f32x4*)(p + 4);
  return packbf2(a, b);
}
#define MFMA(a,b,c) __builtin_amdgcn_mfma_f32_16x16x32_bf16(a,b,c,0,0,0)

__device__ __forceinline__ float fsig(float x){
  return __builtin_amdgcn_rcpf(1.f + __expf(-x));
}
__device__ __forceinline__ float ftanh(float x){
  float e2 = __expf(2.f * x);
  return 1.f - 2.f * __builtin_amdgcn_rcpf(e2 + 1.f);
}

// ---- coherent LLC helpers ----
// Reads: relaxed agent-scope loads (sc0+sc1 -> read the LLC directly).
__device__ __forceinline__ bf16x8 aload_bf8(const unsigned short* p){
  union { u64 u[2]; bf16x8 v; } t;
  t.u[0] = __hip_atomic_load((const u64*)p,     __ATOMIC_RELAXED, __HIP_MEMORY_SCOPE_AGENT);
  t.u[1] = __hip_atomic_load((const u64*)(p+4), __ATOMIC_RELAXED, __HIP_MEMORY_SCOPE_AGENT);
  return t.v;
}
struct fpair { float x, y; };
__device__ __forceinline__ fpair aload_f2(const float* p){
  u64 u = __hip_atomic_load((const u64*)p, __ATOMIC_RELAXED, __HIP_MEMORY_SCOPE_AGENT);
  fpair r;
  r.x = __builtin_bit_cast(float, (unsigned)u);
  r.y = __builtin_bit_cast(float, (unsigned)(u >> 32));
  return r;
}
__device__ __forceinline__ float aload_f(const float* p){
  return __hip_atomic_load(p, __ATOMIC_RELAXED, __HIP_MEMORY_SCOPE_AGENT);
}
// Writes: atomic RMW WITH CONSUMED RETURN -> cannot retire (vmcnt) until the
// LLC has executed it. __syncthreads (s_waitcnt vmcnt(0)) before the barrier
// arrive therefore guarantees commit at the coherence point. This is the fix
// for R7's posted-write race (fire-and-forget stores overtaken by the arrive).
__device__ __forceinline__ u64 astore_bf4r(unsigned short* p, f32x4 x){
  union { unsigned short s[4]; u64 u; } t;
  t.s[0]=f2bf(x[0]); t.s[1]=f2bf(x[1]); t.s[2]=f2bf(x[2]); t.s[3]=f2bf(x[3]);
  return __hip_atomic_exchange((u64*)p, t.u, __ATOMIC_RELAXED, __HIP_MEMORY_SCOPE_AGENT);
}
__device__ __forceinline__ u64 azero8r(u64* p){
  return __hip_atomic_exchange(p, 0ull, __ATOMIC_RELAXED, __HIP_MEMORY_SCOPE_AGENT);
}
__device__ __forceinline__ float afaddr(float* p, float v){
  return __hip_atomic_fetch_add(p, v, __ATOMIC_RELAXED, __HIP_MEMORY_SCOPE_AGENT);
}

// ---------------------------------------------------------------------------
// Pre-pass: tp[pos][a] = (embedding[token] . Wt[a,:]) + bt[a], stored bf16.
// ---------------------------------------------------------------------------
__global__ __launch_bounds__(256) void k_tp(
    const int* __restrict__ tok, const float* __restrict__ emb,
    const float* __restrict__ Wt, const float* __restrict__ bt,
    unsigned short* __restrict__ tp)
{
  const int lane = threadIdx.x & 63;
  const int w = threadIdx.x >> 6;
  const int m16 = lane & 15, quad = lane >> 4;

  bf16x8 wfq[8][4];
#pragma unroll
  for (int kc = 0; kc < 8; kc++)
#pragma unroll
    for (int nt = 0; nt < 4; nt++)
      wfq[kc][nt] = loadB_f32(Wt + (nt*16 + m16)*NE + kc*32 + quad*8);

  float btv[4];
#pragma unroll
  for (int nt = 0; nt < 4; nt++) btv[nt] = bt[nt*16 + m16];

  const int gw = blockIdx.x * 4 + w;
#pragma unroll 1
  for (int it = 0; it < 4; it++){
    const int pt = gw * 4 + it;
    const int pos = pt*16 + m16;
    const long row = (long)tok[pos];
    const float* xrow = emb + row * NE;
    f32x4 acc[4] = {{0,0,0,0},{0,0,0,0},{0,0,0,0},{0,0,0,0}};
#pragma unroll
    for (int kc = 0; kc < 8; kc++){
      bf16x8 af = loadB_f32(xrow + kc*32 + quad*8);
#pragma unroll
      for (int nt = 0; nt < 4; nt++)
        acc[nt] = MFMA(af, wfq[kc][nt], acc[nt]);
    }
#pragma unroll
    for (int nt = 0; nt < 4; nt++)
#pragma unroll
      for (int r = 0; r < 4; r++){
        int posr = pt*16 + quad*4 + r;
        tp[(long)posr * NA + nt*16 + m16] = f2bf(acc[nt][r] + btv[nt]);
      }
  }
}

// ---------------------------------------------------------------------------
struct KArgs {
  const int* len;
  const float* Wq; const float* bq; const float* v; const float* bv;
  const float* Wih0; const float* Whh0; const float* bih0; const float* bhh0;
  const float* Wih1; const float* Whh1; const float* bih1; const float* bhh1;
  const unsigned short* tp;
  unsigned short* h0b; unsigned short* h1b;
  float* ctxg; float* deng;
  int* ctrl;
  float* out;
};

// Fence-free group barrier. Sound because all cross-block WRITES are
// returning RMWs drained (vmcnt) by the preceding __syncthreads -> committed
// at the LLC before the arrive-add is issued.
__device__ __forceinline__ void gbar(int* cnt, int& ep){
  __syncthreads();
  ep++;
  if (threadIdx.x == 0){
    __hip_atomic_fetch_add(cnt, 1, __ATOMIC_RELAXED, __HIP_MEMORY_SCOPE_AGENT);
    const int tgt = WPG * ep;
    while (__hip_atomic_load(cnt, __ATOMIC_RELAXED, __HIP_MEMORY_SCOPE_AGENT) < tgt)
      __builtin_amdgcn_s_sleep(1);
  }
  __syncthreads();
}

__global__ __launch_bounds__(256, 1) void k_main(KArgs A_)
{
  const int tid = threadIdx.x, lane = tid & 63, w = tid >> 6;
  const int g = blockIdx.x & 7, m = blockIdx.x >> 3;   // group, member
  const int m16 = lane & 15, quad = lane >> 4;

  __shared__ __attribute__((aligned(16))) float dslab[6][256]; // gate D staging
  __shared__ __attribute__((aligned(16))) float qs[16][68];    // q[b][a], padded

  unsigned short* h0b = A_.h0b + g * GB * NH;   // bf16 [b][dim]
  unsigned short* h1b = A_.h1b + g * GB * NH;
  float* ctxg = A_.ctxg + g * GB * NA;
  float* deng = A_.deng + g * GB;
  int* bar    = A_.ctrl + g * 64;
  const int b0 = g * GB;

  u64  usink = 0;   // consumes RMW returns so the compiler emits returning ops
  float fsink = 0.f;

  // ----- persistent weight fragments (registers; 1 block/CU by design) -----
  bf16x8 wf[64], wih0f[2];
  float bhh0v[4], bih0v[4], bhh1v[4], bih1v[4], bqv2[4][4];
  if (w < 3){
    const int r0 = w * NH + m * 16;
#pragma unroll
    for (int kc = 0; kc < 16; kc++){
      wf[kc]    = loadB_f32(A_.Whh0 + (long)(r0 + m16)*NH + kc*32 + quad*8);
      wf[16+kc] = loadB_f32(A_.Whh1 + (long)(r0 + m16)*NH + kc*32 + quad*8);
      wf[32+kc] = loadB_f32(A_.Wih1 + (long)(r0 + m16)*NH + kc*32 + quad*8);
    }
#pragma unroll
    for (int kc = 0; kc < 2; kc++)
      wih0f[kc] = loadB_f32(A_.Wih0 + (r0 + m16)*NA + kc*32 + quad*8);
#pragma unroll
    for (int r = 0; r < 4; r++){
      int d = r0 + quad*4 + r;
      bhh0v[r] = A_.bhh0[d]; bih0v[r] = A_.bih0[d];
      bhh1v[r] = A_.bhh1[d]; bih1v[r] = A_.bih1[d];
    }
  } else {
#pragma unroll
    for (int nt = 0; nt < 4; nt++){
#pragma unroll
      for (int kc = 0; kc < 16; kc++)
        wf[nt*16+kc] = loadB_f32(A_.Wq + (long)(nt*16 + m16)*NH + kc*32 + quad*8);
#pragma unroll
      for (int r = 0; r < 4; r++) bqv2[nt][r] = A_.bq[nt*16 + quad*4 + r];
    }
  }

  // attention constants: lane = (a4=quad, t16=m16); wave handles batch ab
  float vv[16];
#pragma unroll
  for (int jj = 0; jj < 16; jj++) vv[jj] = A_.v[quad*16 + jj];
  const float bvv = A_.bv[0];
  const int gwav = m*4 + w;
  const int ab = gwav & 15;   // batch within group
  const int wr = gwav >> 4;   // chunk phase 0..7

  // ----- init shared state (committed RMW stores) -----
  f32x4 h0p = {0,0,0,0}, h1p = {0,0,0,0};
  if (w == 3){
    f32x4 z = {0,0,0,0};
    usink += astore_bf4r(&h0b[m16*NH + m*16 + quad*4], z);
    usink += astore_bf4r(&h1b[m16*NH + m*16 + quad*4], z);
  }
  if (w == 1){
    if (lane < 16) usink += azero8r((u64*)ctxg + m*16 + lane);
    if (lane == 16 && m < 8) usink += azero8r((u64*)deng + m);
  }

  // lengths -> per-batch output step + group max
  int myidx = 0, imax = 0;
#pragma unroll 1
  for (int b = 0; b < GB; b++){
    int L = A_.len[b0 + b];
    int ix = L - 2; ix = ix < 0 ? 0 : (ix > NT-1 ? NT-1 : ix);
    if (b == m16) myidx = ix;
    imax = imax > ix ? imax : ix;
  }

  int ep = 0;
  gbar(bar, ep);   // init barrier (drains init RMWs)

#pragma unroll 1
  for (int i = 0; i <= imax; i++){
    const unsigned short* hb0 = h0b + m16*NH;
    const unsigned short* hb1 = h1b + m16*NH;
    // ============ Phase A: gh0, gh1 (w<3) / q (w==3) ============
    f32x4 gh1 = {0,0,0,0};
    if (w < 3){
      f32x4 gh0 = {0,0,0,0};
#pragma unroll
      for (int kc = 0; kc < 16; kc++){
        bf16x8 b0f = aload_bf8(hb0 + kc*32 + quad*8);
        gh0 = MFMA(wf[kc], b0f, gh0);
        bf16x8 b1f = aload_bf8(hb1 + kc*32 + quad*8);
        gh1 = MFMA(wf[16+kc], b1f, gh1);
      }
#pragma unroll
      for (int r = 0; r < 4; r++){ gh0[r] += bhh0v[r]; gh1[r] += bhh1v[r]; }
      *(f32x4*)&dslab[w][lane*4] = gh0;
    } else {
      bf16x8 b1f[16];
#pragma unroll
      for (int kc = 0; kc < 16; kc++) b1f[kc] = aload_bf8(hb1 + kc*32 + quad*8);
#pragma unroll
      for (int nt = 0; nt < 4; nt++){
        f32x4 qa = {0,0,0,0};
#pragma unroll
        for (int kc = 0; kc < 16; kc++)
          qa = MFMA(wf[nt*16+kc], b1f[kc], qa);
#pragma unroll
        for (int r = 0; r < 4; r++)
          qs[m16][nt*16 + quad*4 + r] = qa[r] + bqv2[nt][r];
      }
    }
    __syncthreads();   // q ready in LDS

    // ============ Phase B: attention for batch ab ============
    float qv[16];
#pragma unroll
    for (int jq = 0; jq < 4; jq++){
      f32x4 t = *(const f32x4*)&qs[ab][quad*16 + jq*4];
      qv[jq*4+0]=t[0]; qv[jq*4+1]=t[1]; qv[jq*4+2]=t[2]; qv[jq*4+3]=t[3];
    }
    float ctxp[16];
#pragma unroll
    for (int jj = 0; jj < 16; jj++) ctxp[jj] = 0.f;
    float denp = 0.f;
    const unsigned short* tpb = A_.tp + (long)(b0 + ab) * NT * NA;
#pragma unroll 1
    for (int c = wr; c*16 <= i; c += 8){
      const int t = c*16 + m16;
      const unsigned short* tpp = tpb + (long)t*NA + quad*16;
      u16x8 ta = *(const u16x8*)tpp;
      u16x8 tb = *(const u16x8*)(tpp + 8);
      float tpf[16];
#pragma unroll
      for (int jj = 0; jj < 8; jj++){ tpf[jj] = bf2f(ta[jj]); tpf[8+jj] = bf2f(tb[jj]); }
      float sp = 0.f;
#pragma unroll
      for (int jj = 0; jj < 16; jj++){
        float x = tpf[jj] + qv[jj];
        sp = fmaf(ftanh(x), vv[jj], sp);
      }
      sp += __shfl_xor(sp, 16);
      sp += __shfl_xor(sp, 32);
      float e = __expf(sp + bvv);
      e = (t <= i) ? e : 0.f;
      denp += e;
#pragma unroll
      for (int jj = 0; jj < 16; jj++) ctxp[jj] = fmaf(e, tpf[jj], ctxp[jj]);
    }
#pragma unroll
    for (int off = 1; off < 64; off <<= 1) denp += __shfl_xor(denp, off);
    denp *= 0.25f;
#pragma unroll
    for (int st = 0; st < 4; st++){
      const int bit = 1 << st;
      const bool up = (lane >> st) & 1;
      const int n2 = (16 >> st) >> 1;
#pragma unroll
      for (int j2 = 0; j2 < 8; j2++){
        if (j2 < n2){
          float keep = up ? ctxp[2*j2+1] : ctxp[2*j2];
          float send = up ? ctxp[2*j2]   : ctxp[2*j2+1];
          float got = __shfl_xor(send, bit);
          ctxp[j2] = keep + got;
        }
      }
    }
    fsink += afaddr(&ctxg[ab*NA + lane], ctxp[0]);
    if (lane == 0) fsink += afaddr(&deng[ab], denp);

    gbar(bar, ep);   // J2: ctx/den committed

    // ============ Phase C: gi0 + layer-0 combine ============
    if (w < 3){
      f32x4 gi0 = {0,0,0,0};
      const float rdn = 1.0f / aload_f(&deng[m16]);
#pragma unroll
      for (int kc = 0; kc < 2; kc++){
        const float* cp = &ctxg[m16*NA + kc*32 + quad*8];
        f32x4 c0, c1;
        fpair p0 = aload_f2(cp+0); c0[0]=p0.x; c0[1]=p0.y;
        fpair p1 = aload_f2(cp+2); c0[2]=p1.x; c0[3]=p1.y;
        fpair p2 = aload_f2(cp+4); c1[0]=p2.x; c1[1]=p2.y;
        fpair p3 = aload_f2(cp+6); c1[2]=p3.x; c1[3]=p3.y;
#pragma unroll
        for (int r = 0; r < 4; r++){ c0[r] *= rdn; c1[r] *= rdn; }
        gi0 = MFMA(wih0f[kc], packbf2(c0, c1), gi0);
      }
#pragma unroll
      for (int r = 0; r < 4; r++) gi0[r] += bih0v[r];
      *(f32x4*)&dslab[3+w][lane*4] = gi0;
    }
    __syncthreads();
    if (w == 3){
      f32x4 ghr = *(f32x4*)&dslab[0][lane*4];
      f32x4 ghz = *(f32x4*)&dslab[1][lane*4];
      f32x4 ghn = *(f32x4*)&dslab[2][lane*4];
      f32x4 gir = *(f32x4*)&dslab[3][lane*4];
      f32x4 giz = *(f32x4*)&dslab[4][lane*4];
      f32x4 gin = *(f32x4*)&dslab[5][lane*4];
      f32x4 hn;
#pragma unroll
      for (int r = 0; r < 4; r++){
        float rr = fsig(gir[r] + ghr[r]);
        float zz = fsig(giz[r] + ghz[r]);
        float nn = ftanh(gin[r] + rr*ghn[r]);
        hn[r] = (1.f - zz)*nn + zz*h0p[r];
      }
      h0p = hn;
      usink += astore_bf4r(&h0b[m16*NH + m*16 + quad*4], hn);
    }
    gbar(bar, ep);   // J3: h0 committed

    // ============ Phase D: gi1 + layer-1 combine ============
    if (w < 3){
      f32x4 gi1 = {0,0,0,0};
#pragma unroll
      for (int kc = 0; kc < 16; kc++){
        bf16x8 bfr = aload_bf8(hb0 + kc*32 + quad*8);
        gi1 = MFMA(wf[32+kc], bfr, gi1);
      }
#pragma unroll
      for (int r = 0; r < 4; r++) gi1[r] += bih1v[r];
      *(f32x4*)&dslab[w][lane*4] = gh1;
      *(f32x4*)&dslab[3+w][lane*4] = gi1;
    }
    if (w == 1){
      // full clear of ctx/den for next step (readers done before J3)
      if (lane < 16) usink += azero8r((u64*)ctxg + m*16 + lane);
      if (lane == 16 && m < 8) usink += azero8r((u64*)deng + m);
    }
    __syncthreads();
    if (w == 3){
      f32x4 ghr = *(f32x4*)&dslab[0][lane*4];
      f32x4 ghz = *(f32x4*)&dslab[1][lane*4];
      f32x4 ghn = *(f32x4*)&dslab[2][lane*4];
      f32x4 gir = *(f32x4*)&dslab[3][lane*4];
      f32x4 giz = *(f32x4*)&dslab[4][lane*4];
      f32x4 gin = *(f32x4*)&dslab[5][lane*4];
      f32x4 hn;
#pragma unroll
      for (int r = 0; r < 4; r++){
        float rr = fsig(gir[r] + ghr[r]);
        float zz = fsig(giz[r] + ghz[r]);
        float nn = ftanh(gin[r] + rr*ghn[r]);
        hn[r] = (1.f - zz)*nn + zz*h1p[r];
      }
      h1p = hn;
      usink += astore_bf4r(&h1b[m16*NH + m*16 + quad*4], hn);
      if (i == myidx)
        *(f32x4*)&A_.out[(long)(b0 + m16)*NH + m*16 + quad*4] = hn;
    }
    gbar(bar, ep);   // J4: h1 committed
  }

  // keep the RMW returns alive (never true: len values are clipped to [4,512])
  u64 total = usink + (u64)__builtin_bit_cast(unsigned, fsink);
  if (total == 0x9e3779b97f4a7c15ull && A_.len[0] == -12345)
    A_.ctrl[56 + g] = (int)total;
}

// ---------------------------------------------------------------------------
extern "C" void kernel_launch(void* const* d_in, const int* in_sizes, int n_in,
                              void* d_out, int out_size, void* d_ws, size_t ws_size,
                              hipStream_t stream)
{
  (void)in_sizes; (void)n_in; (void)out_size; (void)ws_size;
  char* ws = (char*)d_ws;
  unsigned short* tp  = (unsigned short*)ws;                   // 8 MB
  unsigned short* h0b = (unsigned short*)(ws + 8388608);       // 128 KB
  unsigned short* h1b = h0b + NB*NH;                           // 128 KB
  float* ctxg = (float*)(h1b + NB*NH);                         // 32 KB
  float* deng = ctxg + NB*NA;                                  // 512 B -> pad 4 KB
  int* ctrl   = (int*)((char*)deng + 4096);                    // 2 KB

  (void)hipMemsetAsync(ctrl, 0, 2048, stream);

  k_tp<<<dim3(256), dim3(256), 0, stream>>>(
      (const int*)d_in[0], (const float*)d_in[2], (const float*)d_in[3],
      (const float*)d_in[4], tp);

  KArgs ka;
  ka.len  = (const int*)d_in[1];
  ka.Wq   = (const float*)d_in[5];  ka.bq   = (const float*)d_in[6];
  ka.v    = (const float*)d_in[7];  ka.bv   = (const float*)d_in[8];
  ka.Wih0 = (const float*)d_in[9];  ka.Whh0 = (const float*)d_in[10];
  ka.bih0 = (const float*)d_in[11]; ka.bhh0 = (const float*)d_in[12];
  ka.Wih1 = (const float*)d_in[13]; ka.Whh1 = (const float*)d_in[14];
  ka.bih1 = (const float*)d_in[15]; ka.bhh1 = (const float*)d_in[16];
  ka.tp = tp; ka.h0b = h0b; ka.h1b = h1b; ka.ctxg = ctxg; ka.deng = deng;
  ka.ctrl = ctrl; ka.out = (float*)d_out;

  k_main<<<dim3(256), dim3(256), 0, stream>>>(ka);
}

// Round 9
// 8137.055 us; speedup vs baseline: 2.9410x; 1.3469x over previous
//
#include <hip/hip_runtime.h>

#define NB 128
#define NT 512
#define NE 256
#define NH 512
#define NA 64
#define NG 8      // groups (one per XCD via blockIdx%8)
#define WPG 32    // workgroups per group
#define GB 16     // batches per group

typedef short bf16x8 __attribute__((ext_vector_type(8)));
typedef float f32x4 __attribute__((ext_vector_type(4)));
typedef unsigned short u16x8 __attribute__((ext_vector_type(8)));
typedef unsigned long long u64;

__device__ __forceinline__ unsigned short f2bf(float f){
  unsigned u = __builtin_bit_cast(unsigned, f);
  u = u + 0x7fffu + ((u >> 16) & 1u);
  return (unsigned short)(u >> 16);
}
__device__ __forceinline__ float bf2f(unsigned short h){
  unsigned u = ((unsigned)h) << 16;
  return __builtin_bit_cast(float, u);
}
__device__ __forceinline__ bf16x8 packbf2(f32x4 a, f32x4 b){
  bf16x8 r;
  r[0]=(short)f2bf(a[0]); r[1]=(short)f2bf(a[1]); r[2]=(short)f2bf(a[2]); r[3]=(short)f2bf(a[3]);
  r[4]=(short)f2bf(b[0]); r[5]=(short)f2bf(b[1]); r[6]=(short)f2bf(b[2]); r[7]=(short)f2bf(b[3]);
  return r;
}
__device__ __forceinline__ bf16x8 loadB_f32(const float* p){
  f32x4 a = *(const f32x4*)p;
  f32x4 b = *(const f32x4*)(p + 4);
  return packbf2(a, b);
}
#define MFMA(a,b,c) __builtin_amdgcn_mfma_f32_16x16x32_bf16(a,b,c,0,0,0)

__device__ __forceinline__ float fsig(float x){
  return __builtin_amdgcn_rcpf(1.f + __expf(-x));
}
__device__ __forceinline__ float ftanh(float x){
  float e2 = __expf(2.f * x);
  return 1.f - 2.f * __builtin_amdgcn_rcpf(e2 + 1.f);
}

// ---- coherent LLC helpers ----
struct fpair { float x, y; };
__device__ __forceinline__ fpair aload_f2(const float* p){
  u64 u = __hip_atomic_load((const u64*)p, __ATOMIC_RELAXED, __HIP_MEMORY_SCOPE_AGENT);
  fpair r;
  r.x = __builtin_bit_cast(float, (unsigned)u);
  r.y = __builtin_bit_cast(float, (unsigned)(u >> 32));
  return r;
}
__device__ __forceinline__ float aload_f(const float* p){
  return __hip_atomic_load(p, __ATOMIC_RELAXED, __HIP_MEMORY_SCOPE_AGENT);
}
// Writes: atomic RMW with consumed return -> retires only after LLC commit;
// __syncthreads' s_waitcnt vmcnt(0) before the barrier arrive guarantees
// commit at the coherence point (R8-proven protocol).
__device__ __forceinline__ u64 astore_bf4r(unsigned short* p, f32x4 x){
  union { unsigned short s[4]; u64 u; } t;
  t.s[0]=f2bf(x[0]); t.s[1]=f2bf(x[1]); t.s[2]=f2bf(x[2]); t.s[3]=f2bf(x[3]);
  return __hip_atomic_exchange((u64*)p, t.u, __ATOMIC_RELAXED, __HIP_MEMORY_SCOPE_AGENT);
}
__device__ __forceinline__ u64 azero8r(u64* p){
  return __hip_atomic_exchange(p, 0ull, __ATOMIC_RELAXED, __HIP_MEMORY_SCOPE_AGENT);
}
__device__ __forceinline__ float afaddr(float* p, float v){
  return __hip_atomic_fetch_add(p, v, __ATOMIC_RELAXED, __HIP_MEMORY_SCOPE_AGENT);
}

// ---------------------------------------------------------------------------
// Pre-pass: tp[pos][a] = (embedding[token] . Wt[a,:]) + bt[a], stored bf16.
// ---------------------------------------------------------------------------
__global__ __launch_bounds__(256) void k_tp(
    const int* __restrict__ tok, const float* __restrict__ emb,
    const float* __restrict__ Wt, const float* __restrict__ bt,
    unsigned short* __restrict__ tp)
{
  const int lane = threadIdx.x & 63;
  const int w = threadIdx.x >> 6;
  const int m16 = lane & 15, quad = lane >> 4;

  bf16x8 wfq[8][4];
#pragma unroll
  for (int kc = 0; kc < 8; kc++)
#pragma unroll
    for (int nt = 0; nt < 4; nt++)
      wfq[kc][nt] = loadB_f32(Wt + (nt*16 + m16)*NE + kc*32 + quad*8);

  float btv[4];
#pragma unroll
  for (int nt = 0; nt < 4; nt++) btv[nt] = bt[nt*16 + m16];

  const int gw = blockIdx.x * 4 + w;
#pragma unroll 1
  for (int it = 0; it < 4; it++){
    const int pt = gw * 4 + it;
    const int pos = pt*16 + m16;
    const long row = (long)tok[pos];
    const float* xrow = emb + row * NE;
    f32x4 acc[4] = {{0,0,0,0},{0,0,0,0},{0,0,0,0},{0,0,0,0}};
#pragma unroll
    for (int kc = 0; kc < 8; kc++){
      bf16x8 af = loadB_f32(xrow + kc*32 + quad*8);
#pragma unroll
      for (int nt = 0; nt < 4; nt++)
        acc[nt] = MFMA(af, wfq[kc][nt], acc[nt]);
    }
#pragma unroll
    for (int nt = 0; nt < 4; nt++)
#pragma unroll
      for (int r = 0; r < 4; r++){
        int posr = pt*16 + quad*4 + r;
        tp[(long)posr * NA + nt*16 + m16] = f2bf(acc[nt][r] + btv[nt]);
      }
  }
}

// ---------------------------------------------------------------------------
// Pre-pass 2: pack Wq into bf16 MFMA A-fragment blob. blob[((nt*16+kc)*64+lane)*8]
// ---------------------------------------------------------------------------
__global__ __launch_bounds__(256) void k_pack(
    const float* __restrict__ Wq, unsigned short* __restrict__ blob)
{
  const int lane = threadIdx.x & 63, wv = threadIdx.x >> 6;
  const int m16 = lane & 15, quad = lane >> 4;
#pragma unroll
  for (int kc = 0; kc < 16; kc++){
    bf16x8 t = loadB_f32(Wq + (long)(wv*16 + m16)*NH + kc*32 + quad*8);
    *(bf16x8*)&blob[((wv*16 + kc)*64 + lane)*8] = t;
  }
}

// ---------------------------------------------------------------------------
struct KArgs {
  const int* len;
  const float* bq; const float* v; const float* bv;
  const float* Wih0; const float* Whh0; const float* bih0; const float* bhh0;
  const float* Wih1; const float* Whh1; const float* bih1; const float* bhh1;
  const unsigned short* tp;
  const unsigned short* wqblob;
  unsigned short* h0b; unsigned short* h1b;
  float* ctxg; float* deng;
  int* ctrl;
  float* out;
};

__device__ __forceinline__ void gbar(int* cnt, int& ep){
  __syncthreads();
  ep++;
  if (threadIdx.x == 0){
    __hip_atomic_fetch_add(cnt, 1, __ATOMIC_RELAXED, __HIP_MEMORY_SCOPE_AGENT);
    const int tgt = WPG * ep;
    while (__hip_atomic_load(cnt, __ATOMIC_RELAXED, __HIP_MEMORY_SCOPE_AGENT) < tgt)
      __builtin_amdgcn_s_sleep(1);
  }
  __syncthreads();
}

// Cooperative h-state staging: 256 threads pull 16KB (16 batches x 512 bf16)
// from LLC into fragment-ordered LDS [kc][lane][8]. One pass, fully parallel.
__device__ __forceinline__ void stage_h(const unsigned short* hb,
                                        unsigned short (*hs)[64][8], int tid){
  const int lane = tid & 63, wv = tid >> 6;
  const int b = lane & 15, quad = lane >> 4;
#pragma unroll
  for (int c = 0; c < 4; c++){
    const int kc = wv*4 + c;
    const unsigned short* src = hb + b*NH + kc*32 + quad*8;
    union { u64 u[2]; bf16x8 v; } t;
    t.u[0] = __hip_atomic_load((const u64*)src,     __ATOMIC_RELAXED, __HIP_MEMORY_SCOPE_AGENT);
    t.u[1] = __hip_atomic_load((const u64*)(src+4), __ATOMIC_RELAXED, __HIP_MEMORY_SCOPE_AGENT);
    *(bf16x8*)&hs[kc][lane][0] = t.v;
  }
}

__global__ __launch_bounds__(256, 1) void k_main(KArgs A_)
{
  const int tid = threadIdx.x, lane = tid & 63, w = tid >> 6;
  const int g = blockIdx.x & 7, m = blockIdx.x >> 3;   // group, member
  const int m16 = lane & 15, quad = lane >> 4;

  __shared__ __attribute__((aligned(16))) unsigned short h0s[16][64][8]; // 16KB frag order
  __shared__ __attribute__((aligned(16))) unsigned short h1s[16][64][8]; // 16KB
  __shared__ __attribute__((aligned(16))) float dslab[6][256];           // gate D staging
  __shared__ __attribute__((aligned(16))) float qs[16][68];              // q[b][a], padded

  unsigned short* h0b = A_.h0b + g * GB * NH;   // bf16 [b][dim]
  unsigned short* h1b = A_.h1b + g * GB * NH;
  float* ctxg = A_.ctxg + g * GB * NA;
  float* deng = A_.deng + g * GB;
  int* bar    = A_.ctrl + g * 64;
  const int b0 = g * GB;

  u64  usink = 0;
  float fsink = 0.f;

  // ----- persistent weight fragments (registers; 1 block/CU) -----
  // w<3: wf[0..15]=Whh0, wf[16..31]=Whh1, wf[32..47]=Wih1 (rows w*512+m*16)
  bf16x8 wf[48], wih0f[2];
  float bhh0v[4], bih0v[4], bhh1v[4], bih1v[4];
  if (w < 3){
    const int r0 = w * NH + m * 16;
#pragma unroll
    for (int kc = 0; kc < 16; kc++){
      wf[kc]    = loadB_f32(A_.Whh0 + (long)(r0 + m16)*NH + kc*32 + quad*8);
      wf[16+kc] = loadB_f32(A_.Whh1 + (long)(r0 + m16)*NH + kc*32 + quad*8);
      wf[32+kc] = loadB_f32(A_.Wih1 + (long)(r0 + m16)*NH + kc*32 + quad*8);
    }
#pragma unroll
    for (int kc = 0; kc < 2; kc++)
      wih0f[kc] = loadB_f32(A_.Wih0 + (r0 + m16)*NA + kc*32 + quad*8);
#pragma unroll
    for (int r = 0; r < 4; r++){
      int d = r0 + quad*4 + r;
      bhh0v[r] = A_.bhh0[d]; bih0v[r] = A_.bih0[d];
      bhh1v[r] = A_.bhh1[d]; bih1v[r] = A_.bih1[d];
    }
  }
  // q bias: every wave owns q rows w*16..w*16+16
  float bqw[4];
#pragma unroll
  for (int r = 0; r < 4; r++) bqw[r] = A_.bq[w*16 + quad*4 + r];

  // attention constants: lane = (a4=quad, t16=m16); wave handles batch ab
  float vv[16];
#pragma unroll
  for (int jj = 0; jj < 16; jj++) vv[jj] = A_.v[quad*16 + jj];
  const float bvv = A_.bv[0];
  const int gwav = m*4 + w;
  const int ab = gwav & 15;   // batch within group
  const int wr = gwav >> 4;   // chunk phase 0..7

  // ----- init shared state (committed RMW stores) -----
  f32x4 h0p = {0,0,0,0}, h1p = {0,0,0,0};
  if (w == 3){
    f32x4 z = {0,0,0,0};
    usink += astore_bf4r(&h0b[m16*NH + m*16 + quad*4], z);
    usink += astore_bf4r(&h1b[m16*NH + m*16 + quad*4], z);
  }
  if (w == 1){
    if (lane < 16) usink += azero8r((u64*)ctxg + m*16 + lane);
    if (lane == 16 && m < 8) usink += azero8r((u64*)deng + m);
  }

  // lengths -> per-batch output step + group max
  int myidx = 0, imax = 0;
#pragma unroll 1
  for (int b = 0; b < GB; b++){
    int L = A_.len[b0 + b];
    int ix = L - 2; ix = ix < 0 ? 0 : (ix > NT-1 ? NT-1 : ix);
    if (b == m16) myidx = ix;
    imax = imax > ix ? imax : ix;
  }

  int ep = 0;
  gbar(bar, ep);   // init barrier (drains init RMWs)

  // carried gh0 = Whh0 . h0 + bhh0 (h0_init = 0 -> bias only)
  f32x4 gh0c = {0,0,0,0};
  if (w < 3){
#pragma unroll
    for (int r = 0; r < 4; r++) gh0c[r] = bhh0v[r];
  }

#pragma unroll 1
  for (int i = 0; i <= imax; i++){
    // ---- stage h1 (published at prev J4) into LDS, dedup across waves ----
    stage_h(h1b, h1s, tid);
    __syncthreads();

    // ============ Phase A: gh1 (w<3) + q rows w*16.. (all waves) ============
    f32x4 gh1 = {0,0,0,0};
    {
      f32x4 qa = {0,0,0,0};
      if (w < 3){
#pragma unroll
        for (int kc = 0; kc < 16; kc++){
          bf16x8 b1f = *(const bf16x8*)&h1s[kc][lane][0];
          gh1 = MFMA(wf[16+kc], b1f, gh1);
          bf16x8 af = *(const bf16x8*)&A_.wqblob[((w*16 + kc)*64 + lane)*8];
          qa = MFMA(af, b1f, qa);
        }
#pragma unroll
        for (int r = 0; r < 4; r++) gh1[r] += bhh1v[r];
      } else {
#pragma unroll
        for (int kc = 0; kc < 16; kc++){
          bf16x8 b1f = *(const bf16x8*)&h1s[kc][lane][0];
          bf16x8 af = *(const bf16x8*)&A_.wqblob[((w*16 + kc)*64 + lane)*8];
          qa = MFMA(af, b1f, qa);
        }
      }
#pragma unroll
      for (int r = 0; r < 4; r++)
        qs[m16][w*16 + quad*4 + r] = qa[r] + bqw[r];
    }
    __syncthreads();   // q ready in LDS

    // ============ Phase B: attention for batch ab ============
    float qv[16];
#pragma unroll
    for (int jq = 0; jq < 4; jq++){
      f32x4 t = *(const f32x4*)&qs[ab][quad*16 + jq*4];
      qv[jq*4+0]=t[0]; qv[jq*4+1]=t[1]; qv[jq*4+2]=t[2]; qv[jq*4+3]=t[3];
    }
    float ctxp[16];
#pragma unroll
    for (int jj = 0; jj < 16; jj++) ctxp[jj] = 0.f;
    float denp = 0.f;
    const unsigned short* tpb = A_.tp + (long)(b0 + ab) * NT * NA;
#pragma unroll 1
    for (int c = wr; c*16 <= i; c += 8){
      const int t = c*16 + m16;
      const unsigned short* tpp = tpb + (long)t*NA + quad*16;
      u16x8 ta = *(const u16x8*)tpp;
      u16x8 tb = *(const u16x8*)(tpp + 8);
      float tpf[16];
#pragma unroll
      for (int jj = 0; jj < 8; jj++){ tpf[jj] = bf2f(ta[jj]); tpf[8+jj] = bf2f(tb[jj]); }
      float sp = 0.f;
#pragma unroll
      for (int jj = 0; jj < 16; jj++){
        float x = tpf[jj] + qv[jj];
        sp = fmaf(ftanh(x), vv[jj], sp);
      }
      sp += __shfl_xor(sp, 16);
      sp += __shfl_xor(sp, 32);
      float e = __expf(sp + bvv);
      e = (t <= i) ? e : 0.f;
      denp += e;
#pragma unroll
      for (int jj = 0; jj < 16; jj++) ctxp[jj] = fmaf(e, tpf[jj], ctxp[jj]);
    }
#pragma unroll
    for (int off = 1; off < 64; off <<= 1) denp += __shfl_xor(denp, off);
    denp *= 0.25f;
#pragma unroll
    for (int st = 0; st < 4; st++){
      const int bit = 1 << st;
      const bool up = (lane >> st) & 1;
      const int n2 = (16 >> st) >> 1;
#pragma unroll
      for (int j2 = 0; j2 < 8; j2++){
        if (j2 < n2){
          float keep = up ? ctxp[2*j2+1] : ctxp[2*j2];
          float send = up ? ctxp[2*j2]   : ctxp[2*j2+1];
          float got = __shfl_xor(send, bit);
          ctxp[j2] = keep + got;
        }
      }
    }
    fsink += afaddr(&ctxg[ab*NA + lane], ctxp[0]);
    if (lane == 0) fsink += afaddr(&deng[ab], denp);

    gbar(bar, ep);   // J2: ctx/den committed

    // ============ Phase C: gi0 + layer-0 combine (gh0 is carried) ============
    if (w < 3){
      f32x4 gi0 = {0,0,0,0};
      const float rdn = 1.0f / aload_f(&deng[m16]);
#pragma unroll
      for (int kc = 0; kc < 2; kc++){
        const float* cp = &ctxg[m16*NA + kc*32 + quad*8];
        f32x4 c0, c1;
        fpair p0 = aload_f2(cp+0); c0[0]=p0.x; c0[1]=p0.y;
        fpair p1 = aload_f2(cp+2); c0[2]=p1.x; c0[3]=p1.y;
        fpair p2 = aload_f2(cp+4); c1[0]=p2.x; c1[1]=p2.y;
        fpair p3 = aload_f2(cp+6); c1[2]=p3.x; c1[3]=p3.y;
#pragma unroll
        for (int r = 0; r < 4; r++){ c0[r] *= rdn; c1[r] *= rdn; }
        gi0 = MFMA(wih0f[kc], packbf2(c0, c1), gi0);
      }
#pragma unroll
      for (int r = 0; r < 4; r++) gi0[r] += bih0v[r];
      *(f32x4*)&dslab[w][lane*4] = gh0c;
      *(f32x4*)&dslab[3+w][lane*4] = gi0;
    }
    __syncthreads();
    if (w == 3){
      f32x4 ghr = *(f32x4*)&dslab[0][lane*4];
      f32x4 ghz = *(f32x4*)&dslab[1][lane*4];
      f32x4 ghn = *(f32x4*)&dslab[2][lane*4];
      f32x4 gir = *(f32x4*)&dslab[3][lane*4];
      f32x4 giz = *(f32x4*)&dslab[4][lane*4];
      f32x4 gin = *(f32x4*)&dslab[5][lane*4];
      f32x4 hn;
#pragma unroll
      for (int r = 0; r < 4; r++){
        float rr = fsig(gir[r] + ghr[r]);
        float zz = fsig(giz[r] + ghz[r]);
        float nn = ftanh(gin[r] + rr*ghn[r]);
        hn[r] = (1.f - zz)*nn + zz*h0p[r];
      }
      h0p = hn;
      usink += astore_bf4r(&h0b[m16*NH + m*16 + quad*4], hn);
    }
    gbar(bar, ep);   // J3: h0 committed

    // ============ Phase D: stage h0; gi1 + next-step gh0; layer-1 combine ====
    stage_h(h0b, h0s, tid);
    __syncthreads();
    if (w < 3){
      f32x4 gi1 = {0,0,0,0}, g0 = {0,0,0,0};
#pragma unroll
      for (int kc = 0; kc < 16; kc++){
        bf16x8 hf = *(const bf16x8*)&h0s[kc][lane][0];
        gi1 = MFMA(wf[32+kc], hf, gi1);
        g0  = MFMA(wf[kc],    hf, g0);
      }
#pragma unroll
      for (int r = 0; r < 4; r++){ gi1[r] += bih1v[r]; g0[r] += bhh0v[r]; }
      gh0c = g0;
      *(f32x4*)&dslab[w][lane*4] = gh1;
      *(f32x4*)&dslab[3+w][lane*4] = gi1;
    }
    if (w == 1){
      if (lane < 16) usink += azero8r((u64*)ctxg + m*16 + lane);
      if (lane == 16 && m < 8) usink += azero8r((u64*)deng + m);
    }
    __syncthreads();
    if (w == 3){
      f32x4 ghr = *(f32x4*)&dslab[0][lane*4];
      f32x4 ghz = *(f32x4*)&dslab[1][lane*4];
      f32x4 ghn = *(f32x4*)&dslab[2][lane*4];
      f32x4 gir = *(f32x4*)&dslab[3][lane*4];
      f32x4 giz = *(f32x4*)&dslab[4][lane*4];
      f32x4 gin = *(f32x4*)&dslab[5][lane*4];
      f32x4 hn;
#pragma unroll
      for (int r = 0; r < 4; r++){
        float rr = fsig(gir[r] + ghr[r]);
        float zz = fsig(giz[r] + ghz[r]);
        float nn = ftanh(gin[r] + rr*ghn[r]);
        hn[r] = (1.f - zz)*nn + zz*h1p[r];
      }
      h1p = hn;
      usink += astore_bf4r(&h1b[m16*NH + m*16 + quad*4], hn);
      if (i == myidx)
        *(f32x4*)&A_.out[(long)(b0 + m16)*NH + m*16 + quad*4] = hn;
    }
    gbar(bar, ep);   // J4: h1 committed
  }

  // keep the RMW returns alive (never true: len values are clipped to [4,512])
  u64 total = usink + (u64)__builtin_bit_cast(unsigned, fsink);
  if (total == 0x9e3779b97f4a7c15ull && A_.len[0] == -12345)
    A_.ctrl[56 + g] = (int)total;
}

// ---------------------------------------------------------------------------
extern "C" void kernel_launch(void* const* d_in, const int* in_sizes, int n_in,
                              void* d_out, int out_size, void* d_ws, size_t ws_size,
                              hipStream_t stream)
{
  (void)in_sizes; (void)n_in; (void)out_size; (void)ws_size;
  char* ws = (char*)d_ws;
  unsigned short* tp  = (unsigned short*)ws;                   // 8 MB
  unsigned short* h0b = (unsigned short*)(ws + 8388608);       // 128 KB
  unsigned short* h1b = h0b + NB*NH;                           // 128 KB
  float* ctxg = (float*)(h1b + NB*NH);                         // 32 KB
  float* deng = ctxg + NB*NA;                                  // pad 4 KB
  int* ctrl   = (int*)((char*)deng + 4096);                    // 2 KB
  unsigned short* wqblob = (unsigned short*)((char*)ctrl + 2048); // 64 KB

  (void)hipMemsetAsync(ctrl, 0, 2048, stream);

  k_tp<<<dim3(256), dim3(256), 0, stream>>>(
      (const int*)d_in[0], (const float*)d_in[2], (const float*)d_in[3],
      (const float*)d_in[4], tp);
  k_pack<<<dim3(1), dim3(256), 0, stream>>>((const float*)d_in[5], wqblob);

  KArgs ka;
  ka.len  = (const int*)d_in[1];
  ka.bq   = (const float*)d_in[6];
  ka.v    = (const float*)d_in[7];  ka.bv   = (const float*)d_in[8];
  ka.Wih0 = (const float*)d_in[9];  ka.Whh0 = (const float*)d_in[10];
  ka.bih0 = (const float*)d_in[11]; ka.bhh0 = (const float*)d_in[12];
  ka.Wih1 = (const float*)d_in[13]; ka.Whh1 = (const float*)d_in[14];
  ka.bih1 = (const float*)d_in[15]; ka.bhh1 = (const float*)d_in[16];
  ka.tp = tp; ka.wqblob = wqblob; ka.h0b = h0b; ka.h1b = h1b;
  ka.ctxg = ctxg; ka.deng = deng; ka.ctrl = ctrl; ka.out = (float*)d_out;

  k_main<<<dim3(256), dim3(256), 0, stream>>>(ka);
}